// Round 7
// baseline (333.338 us; speedup 1.0000x reference)
//
#include <hip/hip_runtime.h>

#define DIM 512
#define SEQ 2048
#define MROWS 8192

typedef short short8 __attribute__((ext_vector_type(8)));
typedef float floatx4 __attribute__((ext_vector_type(4)));

__device__ __forceinline__ ushort f2bf(float f) {
  union { float f; unsigned u; } v; v.f = f;
  unsigned r = v.u + 0x7fff + ((v.u >> 16) & 1);
  return (ushort)(r >> 16);
}
__device__ __forceinline__ float bf2f(ushort u) {
  union { unsigned u; float f; } v; v.u = ((unsigned)u) << 16;
  return v.f;
}

// ---------------------------------------------------------------------------
// prep (blocks 0..4095): vis->bf16, xp = x + concat(emb1[c1],emb2[c2]) -> bf16
// wtrans (blocks 4096..4415): Wt[n][k] = W[k][n] bf16, wq pre-scaled 0.125
// ---------------------------------------------------------------------------
__global__ __launch_bounds__(256) void prep_wtrans_kernel(
    const float* __restrict__ x, const float* __restrict__ vis,
    const int* __restrict__ c1, const int* __restrict__ c2,
    const float* __restrict__ e1, const float* __restrict__ e2,
    const float* __restrict__ wq, const float* __restrict__ wk,
    const float* __restrict__ wv, const float* __restrict__ w1,
    const float* __restrict__ w2,
    ushort* __restrict__ xp_bf, ushort* __restrict__ vis_bf,
    ushort* __restrict__ wt_qkv, ushort* __restrict__ wt1,
    ushort* __restrict__ wt2) {
  __shared__ float Ls[64 * 65];
  if (blockIdx.x < 4096) {
    int gid = blockIdx.x * 256 + threadIdx.x;
    int row = gid >> 7;
    int col = (gid & 127) * 4;
    float4 vv = *(const float4*)(vis + (size_t)row * 512 + col);
    ushort4 vb; vb.x = f2bf(vv.x); vb.y = f2bf(vv.y); vb.z = f2bf(vv.z); vb.w = f2bf(vv.w);
    *(ushort4*)(vis_bf + (size_t)row * 512 + col) = vb;
    float4 p;
    if (col < 256) p = *(const float4*)(e1 + (size_t)c1[row] * 256 + col);
    else           p = *(const float4*)(e2 + (size_t)c2[row] * 256 + col - 256);
    float4 xv = *(const float4*)(x + (size_t)row * 512 + col);
    ushort4 xb; xb.x = f2bf(xv.x + p.x); xb.y = f2bf(xv.y + p.y);
    xb.z = f2bf(xv.z + p.z); xb.w = f2bf(xv.w + p.w);
    *(ushort4*)(xp_bf + (size_t)row * 512 + col) = xb;
  } else {
    int bid = blockIdx.x - 4096;
    int mid = bid >> 6;
    int tile = bid & 63;
    int k0 = (tile >> 3) * 64, n0 = (tile & 7) * 64;
    const float* W = mid == 0 ? wq : mid == 1 ? wk : mid == 2 ? wv : mid == 3 ? w1 : w2;
    ushort* outp = mid < 3 ? (wt_qkv + (size_t)mid * 512 * 512) : (mid == 3 ? wt1 : wt2);
    float scale = (mid == 0) ? 0.125f : 1.0f;
    int r = threadIdx.x >> 4, c4 = (threadIdx.x & 15) * 4;
#pragma unroll
    for (int i = 0; i < 4; i++) {
      int row = i * 16 + r;
      float4 wv4 = *(const float4*)(W + (size_t)(k0 + row) * 512 + n0 + c4);
      Ls[row * 65 + c4 + 0] = wv4.x * scale;
      Ls[row * 65 + c4 + 1] = wv4.y * scale;
      Ls[row * 65 + c4 + 2] = wv4.z * scale;
      Ls[row * 65 + c4 + 3] = wv4.w * scale;
    }
    __syncthreads();
    int n = threadIdx.x >> 2, kc = (threadIdx.x & 3) * 16;
    ushort pk[16];
#pragma unroll
    for (int i = 0; i < 16; i++) pk[i] = f2bf(Ls[(kc + i) * 65 + n]);
    ushort* op = outp + (size_t)(n0 + n) * 512 + k0 + kc;
    *(uint4*)op = *(uint4*)pk;
    *(uint4*)(op + 8) = *(uint4*)(pk + 8);
  }
}

// ---------------------------------------------------------------------------
// LDS-free bf16 MFMA GEMM: 64x128 (MxN) tile, all fragments loaded directly
// from global (each 16B load is lane-coalesced; one BK=64 window touches
// exactly one 128B line per row -> 100% sector use; tiles are L2-resident).
// NO barriers in the K-loop -> compiler pipelines loads with vmcnt.
// LDS used only for the store-transpose epilogue (wave-private).
// HEADMAJOR: write out as [B,H,S,64] (for QKV -> attention).
// ---------------------------------------------------------------------------
template <bool LEAKY, bool HEADMAJOR>
__global__ __launch_bounds__(256, 3) void gemm_direct(
    const ushort* __restrict__ A01, const ushort* __restrict__ A2,
    const ushort* __restrict__ Wt,
    const float* __restrict__ bias0, const float* __restrict__ bias1,
    const float* __restrict__ bias2,
    ushort* __restrict__ out0, ushort* __restrict__ out1,
    ushort* __restrict__ out2, float s0scale) {
  __shared__ __align__(16) float Ls[4 * 1088];
  int t = threadIdx.x;
  int seg = blockIdx.x >> 2;
  int nloc0 = (blockIdx.x & 3) * 128;
  int n0w = blockIdx.x * 128;
  int m0 = blockIdx.y * 64;
  const ushort* A = (seg < 2) ? A01 : A2;
  const float* bias = seg == 0 ? bias0 : seg == 1 ? bias1 : bias2;
  ushort* out = seg == 0 ? out0 : seg == 1 ? out1 : out2;
  float bscale = seg == 0 ? s0scale : 1.0f;

  int w = t >> 6, lane = t & 63;
  int wm = (w & 1) * 32, wn = (w >> 1) * 64;
  int quad = lane >> 4, lcol = lane & 15;

  const ushort* Ar0 = A + (size_t)(m0 + wm + lcol) * 512 + quad * 8;
  const ushort* Ar1 = Ar0 + 16 * 512;
  const ushort* Br0 = Wt + (size_t)(n0w + wn + lcol) * 512 + quad * 8;
  const ushort* Br1 = Br0 + 16 * 512;
  const ushort* Br2 = Br0 + 32 * 512;
  const ushort* Br3 = Br0 + 48 * 512;

  floatx4 acc[2][4] = {};

#pragma unroll 4
  for (int k = 0; k < 512; k += 32) {
    short8 a0 = *(const short8*)(Ar0 + k);
    short8 a1 = *(const short8*)(Ar1 + k);
    short8 b0 = *(const short8*)(Br0 + k);
    short8 b1 = *(const short8*)(Br1 + k);
    short8 b2 = *(const short8*)(Br2 + k);
    short8 b3 = *(const short8*)(Br3 + k);
    acc[0][0] = __builtin_amdgcn_mfma_f32_16x16x32_bf16(a0, b0, acc[0][0], 0, 0, 0);
    acc[0][1] = __builtin_amdgcn_mfma_f32_16x16x32_bf16(a0, b1, acc[0][1], 0, 0, 0);
    acc[0][2] = __builtin_amdgcn_mfma_f32_16x16x32_bf16(a0, b2, acc[0][2], 0, 0, 0);
    acc[0][3] = __builtin_amdgcn_mfma_f32_16x16x32_bf16(a0, b3, acc[0][3], 0, 0, 0);
    acc[1][0] = __builtin_amdgcn_mfma_f32_16x16x32_bf16(a1, b0, acc[1][0], 0, 0, 0);
    acc[1][1] = __builtin_amdgcn_mfma_f32_16x16x32_bf16(a1, b1, acc[1][1], 0, 0, 0);
    acc[1][2] = __builtin_amdgcn_mfma_f32_16x16x32_bf16(a1, b2, acc[1][2], 0, 0, 0);
    acc[1][3] = __builtin_amdgcn_mfma_f32_16x16x32_bf16(a1, b3, acc[1][3], 0, 0, 0);
  }

  // epilogue: wave-private LDS transpose -> coalesced 16B bf16 stores
  float* Lw = Ls + w * 1088;  // 16x68
  int rr = lane >> 2, cc = (lane & 3) * 16;
#pragma unroll
  for (int mt = 0; mt < 2; mt++) {
#pragma unroll
    for (int nt = 0; nt < 4; nt++) {
      float bv = bias[nloc0 + wn + nt * 16 + lcol] * bscale;
#pragma unroll
      for (int r = 0; r < 4; r++) {
        float vv = acc[mt][nt][r] + bv;
        if (LEAKY) vv = vv >= 0.f ? vv : 0.2f * vv;
        Lw[(quad * 4 + r) * 68 + nt * 16 + lcol] = vv;
      }
    }
    asm volatile("s_waitcnt lgkmcnt(0)" ::: "memory");
    ushort pk[16];
#pragma unroll
    for (int i = 0; i < 16; i += 4) {
      float4 fv = *(const float4*)(&Lw[rr * 68 + cc + i]);
      pk[i] = f2bf(fv.x); pk[i + 1] = f2bf(fv.y);
      pk[i + 2] = f2bf(fv.z); pk[i + 3] = f2bf(fv.w);
    }
    ushort* op;
    int m = m0 + wm + mt * 16 + rr;
    if (HEADMAJOR) {
      int nseg = nloc0 + wn + cc;          // 0..511 within this output
      int h = nseg >> 6, d = nseg & 63;    // cc group stays within one head
      int b = m >> 11, s = m & 2047;
      op = out + (((size_t)b * 8 + h) * 2048 + s) * 64 + d;
    } else {
      op = out + (size_t)m * 512 + nloc0 + wn + cc;
    }
    *(uint4*)op = *(uint4*)pk;
    *(uint4*)(op + 8) = *(uint4*)(pk + 8);
    asm volatile("s_waitcnt lgkmcnt(0)" ::: "memory");
  }
}

// ---------------------------------------------------------------------------
// MFMA flash attention, static-max softmax. q,k,v HEAD-MAJOR [B,H,S,64]
// (every row = one 128B cacheline; K-tile is a contiguous 16KB block).
// 128 q-rows/block (wave = 32 rows = 2 qm frags), K-tile 128, swizzled LDS.
// kf/vf hoisted out of qm loops: 40 b128 LDS reads per wave per k-tile.
// out is row-major [B,S,512]. grid 512, 2 blocks/CU.
// ---------------------------------------------------------------------------
__global__ __launch_bounds__(256, 2) void attn_mfma_kernel(
    const ushort* __restrict__ q, const ushort* __restrict__ k,
    const ushort* __restrict__ v, ushort* __restrict__ out) {
  __shared__ __align__(16) ushort Ks[128 * 64];    // [krow][dim] swizzled
  __shared__ __align__(16) ushort Vt[64 * 128];    // [dim][krow] swizzled
  __shared__ __align__(16) ushort Ps[4 * 32 * 64]; // wave-private P (half-tile)
  int t = threadIdx.x;
  int blk = blockIdx.x;
  int qt = blk & 15, h = (blk >> 4) & 7, b = blk >> 7;
  int wave = t >> 6, lane = t & 63, quad = lane >> 4, lcol = lane & 15;
  int q0 = qt * 128 + wave * 32;
  const size_t hbase = ((size_t)b * 8 + h) * (SEQ * 64);
  const size_t obase = (size_t)b * SEQ * 512 + h * 64;

  short8 qf[2][2];
#pragma unroll
  for (int qm = 0; qm < 2; qm++)
#pragma unroll
    for (int kc = 0; kc < 2; kc++)
      qf[qm][kc] = *(const short8*)(
          q + hbase + (size_t)(q0 + qm * 16 + lcol) * 64 + kc * 32 + quad * 8);

  floatx4 O[2][4] = {};
  float lsum[2][4] = {};

  ushort* Pw = Ps + wave * (32 * 64);
  int pl = t & 63, dg = t >> 6;

  for (int kt = 0; kt < SEQ; kt += 128) {
    __syncthreads();
    // stage K: contiguous 16KB -> swizzled [krow][64]; 1024 uint4 total
    {
      const ushort* kbase = k + hbase + (size_t)kt * 64;
#pragma unroll
      for (int i = 0; i < 4; i++) {
        int id = i * 256 + t;
        int krow = id >> 3, ch = id & 7;
        *(uint4*)(&Ks[krow * 64 + (ch ^ (krow & 7)) * 8]) =
            *(const uint4*)(kbase + id * 8);
      }
    }
    // stage V transposed: Vt[dim][krow]
    {
      const ushort* vr0 = v + hbase + (size_t)(kt + 2 * pl) * 64 + dg * 16;
      uint4 va[2], vb[2];
      va[0] = *(const uint4*)(vr0); va[1] = *(const uint4*)(vr0 + 8);
      vb[0] = *(const uint4*)(vr0 + 64); vb[1] = *(const uint4*)(vr0 + 72);
      const ushort* a0 = (const ushort*)va;
      const ushort* a1 = (const ushort*)vb;
#pragma unroll
      for (int i = 0; i < 16; i++) {
        int dim = dg * 16 + i;
        unsigned pack = (unsigned)a0[i] | ((unsigned)a1[i] << 16);
        int pch = (pl >> 2) ^ (dim & 7);
        *(unsigned*)(&Vt[dim * 128 + pch * 8 + (pl & 3) * 2]) = pack;
      }
    }
    __syncthreads();

#pragma unroll
    for (int half = 0; half < 2; half++) {
      // QK^T: kf shared across both qm frags
      floatx4 S[2][4] = {};
#pragma unroll
      for (int kc = 0; kc < 2; kc++) {
        int pch = ((kc * 4 + quad) ^ (lcol & 7)) * 8;
#pragma unroll
        for (int jt4 = 0; jt4 < 4; jt4++) {
          int jrow = (half * 4 + jt4) * 16 + lcol;
          short8 kf = *(const short8*)(&Ks[jrow * 64 + pch]);
          S[0][jt4] = __builtin_amdgcn_mfma_f32_16x16x32_bf16(
              qf[0][kc], kf, S[0][jt4], 0, 0, 0);
          S[1][jt4] = __builtin_amdgcn_mfma_f32_16x16x32_bf16(
              qf[1][kc], kf, S[1][jt4], 0, 0, 0);
        }
      }
      // exp -> P (trunc bf16) in LDS; accumulate row sums
#pragma unroll
      for (int qm = 0; qm < 2; qm++)
#pragma unroll
        for (int jt4 = 0; jt4 < 4; jt4++)
#pragma unroll
          for (int r = 0; r < 4; r++) {
            float p = __expf(S[qm][jt4][r]);
            lsum[qm][r] += p;
            int prow = qm * 16 + quad * 4 + r;
            int pcol = jt4 * 16 + lcol;
            int pch2 = (pcol >> 3) ^ (prow & 7);
            Pw[prow * 64 + pch2 * 8 + (pcol & 7)] =
                (ushort)(__float_as_uint(p) >> 16);
          }
      asm volatile("s_waitcnt lgkmcnt(0)" ::: "memory");
      // PV: vf shared across both qm frags
#pragma unroll
      for (int kc = 0; kc < 2; kc++) {
        int ppch = ((kc * 4 + quad) ^ (lcol & 7)) * 8;
        short8 pf0 = *(const short8*)(&Pw[(0 * 16 + lcol) * 64 + ppch]);
        short8 pf1 = *(const short8*)(&Pw[(1 * 16 + lcol) * 64 + ppch]);
        int ch = half * 8 + kc * 4 + quad;
        int vch = (ch ^ (lcol & 7)) * 8;
#pragma unroll
        for (int nt = 0; nt < 4; nt++) {
          short8 vf = *(const short8*)(&Vt[(nt * 16 + lcol) * 128 + vch]);
          O[0][nt] = __builtin_amdgcn_mfma_f32_16x16x32_bf16(
              pf0, vf, O[0][nt], 0, 0, 0);
          O[1][nt] = __builtin_amdgcn_mfma_f32_16x16x32_bf16(
              pf1, vf, O[1][nt], 0, 0, 0);
        }
      }
    }
  }

#pragma unroll
  for (int qm = 0; qm < 2; qm++)
#pragma unroll
    for (int r = 0; r < 4; r++) {
#pragma unroll
      for (int m = 1; m <= 8; m <<= 1)
        lsum[qm][r] += __shfl_xor(lsum[qm][r], m, 64);
      lsum[qm][r] = 1.f / lsum[qm][r];
    }
#pragma unroll
  for (int qm = 0; qm < 2; qm++)
#pragma unroll
    for (int nt = 0; nt < 4; nt++)
#pragma unroll
      for (int r = 0; r < 4; r++)
        out[obase + (size_t)(q0 + qm * 16 + quad * 4 + r) * 512 + nt * 16 + lcol] =
            f2bf(O[qm][nt][r] * lsum[qm][r]);
}

// ---------------------------------------------------------------------------
// layernorm over last dim (512), bf16 in; bf16 or fp32 out.
// ---------------------------------------------------------------------------
template <bool OUTF32>
__global__ __launch_bounds__(256) void ln_kernel(
    const ushort* __restrict__ h, const float* __restrict__ g,
    const float* __restrict__ beta, void* __restrict__ outv) {
  int wave = threadIdx.x >> 6, lane = threadIdx.x & 63;
  int row = blockIdx.x * 4 + wave;
  uint4 raw = *(const uint4*)(h + (size_t)row * 512 + lane * 8);
  const ushort* hu = (const ushort*)&raw;
  float vals[8];
#pragma unroll
  for (int i = 0; i < 8; i++) vals[i] = bf2f(hu[i]);
  float sum = 0.f;
#pragma unroll
  for (int i = 0; i < 8; i++) sum += vals[i];
#pragma unroll
  for (int off = 32; off >= 1; off >>= 1) sum += __shfl_xor(sum, off, 64);
  float mean = sum * (1.f / 512.f);
  float vs = 0.f;
#pragma unroll
  for (int i = 0; i < 8; i++) { float d = vals[i] - mean; vs += d * d; }
#pragma unroll
  for (int off = 32; off >= 1; off >>= 1) vs += __shfl_xor(vs, off, 64);
  float rstd = rsqrtf(vs * (1.f / 512.f) + 1e-5f);
  float4 gv0 = *(const float4*)(g + lane * 8);
  float4 gv1 = *(const float4*)(g + lane * 8 + 4);
  float4 bv0 = *(const float4*)(beta + lane * 8);
  float4 bv1 = *(const float4*)(beta + lane * 8 + 4);
  float gr[8] = {gv0.x, gv0.y, gv0.z, gv0.w, gv1.x, gv1.y, gv1.z, gv1.w};
  float br[8] = {bv0.x, bv0.y, bv0.z, bv0.w, bv1.x, bv1.y, bv1.z, bv1.w};
  float res[8];
#pragma unroll
  for (int i = 0; i < 8; i++) res[i] = (vals[i] - mean) * rstd * gr[i] + br[i];
  if (OUTF32) {
    float* op = (float*)outv + (size_t)row * 512 + lane * 8;
    float4 o0, o1;
    o0.x = res[0]; o0.y = res[1]; o0.z = res[2]; o0.w = res[3];
    o1.x = res[4]; o1.y = res[5]; o1.z = res[6]; o1.w = res[7];
    *(float4*)op = o0; *(float4*)(op + 4) = o1;
  } else {
    ushort* op = (ushort*)outv + (size_t)row * 512 + lane * 8;
    ushort4 o0, o1;
    o0.x = f2bf(res[0]); o0.y = f2bf(res[1]); o0.z = f2bf(res[2]); o0.w = f2bf(res[3]);
    o1.x = f2bf(res[4]); o1.y = f2bf(res[5]); o1.z = f2bf(res[6]); o1.w = f2bf(res[7]);
    *(ushort4*)op = o0; *(ushort4*)(op + 4) = o1;
  }
}

// ---------------------------------------------------------------------------
extern "C" void kernel_launch(void* const* d_in, const int* in_sizes, int n_in,
                              void* d_out, int out_size, void* d_ws,
                              size_t ws_size, hipStream_t stream) {
  (void)in_sizes; (void)n_in; (void)out_size; (void)ws_size;
  const float* x     = (const float*)d_in[0];
  const float* vis   = (const float*)d_in[1];
  const int*   c1    = (const int*)d_in[2];
  const int*   c2    = (const int*)d_in[3];
  const float* e1    = (const float*)d_in[4];
  const float* e2    = (const float*)d_in[5];
  const float* wq    = (const float*)d_in[6];
  const float* bq    = (const float*)d_in[7];
  const float* wk    = (const float*)d_in[8];
  const float* bk    = (const float*)d_in[9];
  const float* wv    = (const float*)d_in[10];
  const float* bv    = (const float*)d_in[11];
  const float* w1    = (const float*)d_in[12];
  const float* b1    = (const float*)d_in[13];
  const float* g1    = (const float*)d_in[14];
  const float* beta1 = (const float*)d_in[15];
  const float* w2    = (const float*)d_in[16];
  const float* b2    = (const float*)d_in[17];
  const float* g2    = (const float*)d_in[18];
  const float* beta2 = (const float*)d_in[19];
  float* out = (float*)d_out;
  ushort* ws = (ushort*)d_ws;

  const size_t BUF = (size_t)MROWS * 512;
  ushort* xp_bf  = ws;             // later h1
  ushort* vis_bf = ws + BUF;       // later attn_out
  ushort* q_bf   = ws + 2 * BUF;   // head-major; later ln1
  ushort* k_bf   = ws + 3 * BUF;   // head-major; later h2
  ushort* v_bf   = ws + 4 * BUF;   // head-major
  ushort* wt_qkv = ws + 5 * BUF;
  ushort* wt1    = wt_qkv + 1536 * 512;
  ushort* wt2    = wt1 + 512 * 512;
  ushort* attn_bf = vis_bf;
  ushort* h1_bf   = xp_bf;
  ushort* ln1_bf  = q_bf;
  ushort* h2_bf   = k_bf;

  prep_wtrans_kernel<<<4416, 256, 0, stream>>>(
      x, vis, c1, c2, e1, e2, wq, wk, wv, w1, w2, xp_bf, vis_bf, wt_qkv, wt1, wt2);
  gemm_direct<false, true><<<dim3(12, 128), 256, 0, stream>>>(
      vis_bf, xp_bf, wt_qkv, bq, bk, bv, q_bf, k_bf, v_bf, 0.125f);
  attn_mfma_kernel<<<512, 256, 0, stream>>>(q_bf, k_bf, v_bf, attn_bf);
  gemm_direct<true, false><<<dim3(4, 128), 256, 0, stream>>>(
      attn_bf, attn_bf, wt1, b1, b1, b1, h1_bf, h1_bf, h1_bf, 1.0f);
  ln_kernel<false><<<2048, 256, 0, stream>>>(h1_bf, g1, beta1, ln1_bf);
  gemm_direct<true, false><<<dim3(4, 128), 256, 0, stream>>>(
      ln1_bf, ln1_bf, wt2, b2, b2, b2, h2_bf, h2_bf, h2_bf, 1.0f);
  ln_kernel<true><<<2048, 256, 0, stream>>>(h2_bf, g2, beta2, out);
}